// Round 1
// baseline (707.396 us; speedup 1.0000x reference)
//
#include <hip/hip_runtime.h>
#include <math.h>

#define BB   64
#define SS   4096
#define ENC  512
#define DEC  512
#define NSPLIT 16
#define CHUNK (SS / NSPLIT)   // 256 rows per chunk, 64 rows per wave

// ---------------------------------------------------------------------------
// Kernel 1: sub[b,e] = sum_d dec[b,d] * W[e,d]     (F.linear: dec @ W^T)
// grid (4, B), block 256 (4 waves). Each wave computes 32 outputs e.
// ---------------------------------------------------------------------------
__global__ __launch_bounds__(256) void k_sub(const float* __restrict__ dec,
                                             const float* __restrict__ W,
                                             float* __restrict__ sub) {
    const int b    = blockIdx.y;
    const int lane = threadIdx.x & 63;
    const int wave = threadIdx.x >> 6;

    // lane holds dec[b, lane*8 .. lane*8+7]
    const float4* dv = (const float4*)(dec + (size_t)b * DEC);
    float4 q0 = dv[lane * 2 + 0];
    float4 q1 = dv[lane * 2 + 1];

    const int e0 = blockIdx.x * 128 + wave * 32;
    for (int i = 0; i < 32; ++i) {
        const int e = e0 + i;
        const float4* wv = (const float4*)(W + (size_t)e * DEC);
        float4 w0 = wv[lane * 2 + 0];
        float4 w1 = wv[lane * 2 + 1];
        float p = q0.x * w0.x + q0.y * w0.y + q0.z * w0.z + q0.w * w0.w
                + q1.x * w1.x + q1.y * w1.y + q1.z * w1.z + q1.w * w1.w;
        #pragma unroll
        for (int off = 32; off >= 1; off >>= 1) p += __shfl_xor(p, off, 64);
        if (lane == 0) sub[(size_t)b * ENC + e] = p;
    }
}

// ---------------------------------------------------------------------------
// Kernel 2: fused scores + online softmax + weighted accumulation.
// grid (NSPLIT, B), block 256 (4 waves). Each wave streams CHUNK/4 = 64 rows,
// each row = one coalesced 2 KB load used for BOTH the score dot and the
// weighted accumulation (enc is K and V simultaneously).
// Emits raw scores into the attn output region, and per-chunk (m, l, acc[512]).
// ---------------------------------------------------------------------------
__global__ __launch_bounds__(256) void k_attn(const float* __restrict__ enc,
                                              const float* __restrict__ sub,
                                              float* __restrict__ attn_raw,
                                              float* __restrict__ chunk_m,
                                              float* __restrict__ chunk_l,
                                              float* __restrict__ chunk_acc) {
    const int b    = blockIdx.y;
    const int c    = blockIdx.x;
    const int lane = threadIdx.x & 63;
    const int wave = threadIdx.x >> 6;

    const float4* qv = (const float4*)(sub + (size_t)b * ENC);
    float4 q0 = qv[lane * 2 + 0];
    float4 q1 = qv[lane * 2 + 1];

    float m = -INFINITY, l = 0.f;
    float4 a0 = {0.f, 0.f, 0.f, 0.f};
    float4 a1 = {0.f, 0.f, 0.f, 0.f};

    const int sBase = c * CHUNK;
    #pragma unroll 2
    for (int i = wave; i < CHUNK; i += 4) {
        const int s = sBase + i;
        const float4* ev = (const float4*)(enc + ((size_t)b * SS + s) * ENC);
        float4 e0 = ev[lane * 2 + 0];
        float4 e1 = ev[lane * 2 + 1];

        float p = q0.x * e0.x + q0.y * e0.y + q0.z * e0.z + q0.w * e0.w
                + q1.x * e1.x + q1.y * e1.y + q1.z * e1.z + q1.w * e1.w;
        #pragma unroll
        for (int off = 32; off >= 1; off >>= 1) p += __shfl_xor(p, off, 64);

        if (lane == 0) attn_raw[(size_t)b * SS + s] = p;   // raw score

        const float mn    = fmaxf(m, p);
        const float alpha = __expf(m - mn);   // exp(-inf)=0 handles first iter
        const float w     = __expf(p - mn);
        l = l * alpha + w;
        a0.x = a0.x * alpha + w * e0.x;  a0.y = a0.y * alpha + w * e0.y;
        a0.z = a0.z * alpha + w * e0.z;  a0.w = a0.w * alpha + w * e0.w;
        a1.x = a1.x * alpha + w * e1.x;  a1.y = a1.y * alpha + w * e1.y;
        a1.z = a1.z * alpha + w * e1.z;  a1.w = a1.w * alpha + w * e1.w;
        m = mn;
    }

    // ---- combine the 4 waves of this block ----
    __shared__ float sm[4];
    __shared__ float sl[4];
    __shared__ float sacc[4][ENC];

    if (lane == 0) sm[wave] = m;
    __syncthreads();
    const float M = fmaxf(fmaxf(sm[0], sm[1]), fmaxf(sm[2], sm[3]));
    const float f = __expf(m - M);           // wave-uniform
    if (lane == 0) sl[wave] = l * f;
    float* sa = &sacc[wave][lane * 8];
    sa[0] = a0.x * f; sa[1] = a0.y * f; sa[2] = a0.z * f; sa[3] = a0.w * f;
    sa[4] = a1.x * f; sa[5] = a1.y * f; sa[6] = a1.z * f; sa[7] = a1.w * f;
    __syncthreads();

    const size_t idx = (size_t)b * NSPLIT + c;
    if (threadIdx.x == 0) {
        chunk_m[idx] = M;
        chunk_l[idx] = sl[0] + sl[1] + sl[2] + sl[3];
    }
    for (int e = threadIdx.x; e < ENC; e += 256) {
        chunk_acc[idx * ENC + e] = sacc[0][e] + sacc[1][e] + sacc[2][e] + sacc[3][e];
    }
}

// ---------------------------------------------------------------------------
// Kernel 3: combine chunks -> sumResult; normalize attn in place.
// grid B, block 256. ~3 MB of traffic total — negligible.
// ---------------------------------------------------------------------------
__global__ __launch_bounds__(256) void k_final(const float* __restrict__ chunk_m,
                                               const float* __restrict__ chunk_l,
                                               const float* __restrict__ chunk_acc,
                                               float* __restrict__ attn,
                                               float* __restrict__ sumResult) {
    const int b = blockIdx.x;

    float M = -INFINITY;
    #pragma unroll
    for (int c = 0; c < NSPLIT; ++c) M = fmaxf(M, chunk_m[(size_t)b * NSPLIT + c]);

    float f[NSPLIT];
    float L = 0.f;
    #pragma unroll
    for (int c = 0; c < NSPLIT; ++c) {
        f[c] = __expf(chunk_m[(size_t)b * NSPLIT + c] - M);
        L += chunk_l[(size_t)b * NSPLIT + c] * f[c];
    }
    const float invL = 1.f / L;

    for (int e = threadIdx.x; e < ENC; e += 256) {
        float s = 0.f;
        #pragma unroll
        for (int c = 0; c < NSPLIT; ++c)
            s += chunk_acc[((size_t)b * NSPLIT + c) * ENC + e] * f[c];
        sumResult[(size_t)b * ENC + e] = s * invL;
    }

    for (int s = threadIdx.x; s < SS; s += 256) {
        const size_t i = (size_t)b * SS + s;
        attn[i] = __expf(attn[i] - M) * invL;
    }
}

// ---------------------------------------------------------------------------
extern "C" void kernel_launch(void* const* d_in, const int* in_sizes, int n_in,
                              void* d_out, int out_size, void* d_ws, size_t ws_size,
                              hipStream_t stream) {
    const float* dec = (const float*)d_in[0];   // [B,1,DEC]
    const float* enc = (const float*)d_in[1];   // [B,S,ENC]
    const float* W   = (const float*)d_in[2];   // [ENC,DEC]

    float* out       = (float*)d_out;
    float* attn      = out;                               // B*S
    float* sumResult = out + (size_t)BB * SS;             // B*ENC

    float* ws        = (float*)d_ws;
    float* sub       = ws;                                // B*ENC
    float* chunk_m   = sub + (size_t)BB * ENC;            // B*NSPLIT
    float* chunk_l   = chunk_m + (size_t)BB * NSPLIT;     // B*NSPLIT
    float* chunk_acc = chunk_l + (size_t)BB * NSPLIT;     // B*NSPLIT*ENC

    k_sub  <<<dim3(4, BB),      256, 0, stream>>>(dec, W, sub);
    k_attn <<<dim3(NSPLIT, BB), 256, 0, stream>>>(enc, sub, attn, chunk_m, chunk_l, chunk_acc);
    k_final<<<BB,               256, 0, stream>>>(chunk_m, chunk_l, chunk_acc, attn, sumResult);
}

// Round 2
// 703.495 us; speedup vs baseline: 1.0055x; 1.0055x over previous
//
#include <hip/hip_runtime.h>
#include <math.h>

#define BB   64
#define SS   4096
#define ENC  512
#define DEC  512
#define NSPLIT 32
#define CHUNK (SS / NSPLIT)   // 128 rows per chunk, 32 rows per wave

// ---------------------------------------------------------------------------
// Kernel 1: sub[b,e] = sum_d dec[b,d] * W[e,d]     (F.linear: dec @ W^T)
// grid (4, B), block 256 (4 waves). Each wave computes 32 outputs e.
// ---------------------------------------------------------------------------
__global__ __launch_bounds__(256) void k_sub(const float* __restrict__ dec,
                                             const float* __restrict__ W,
                                             float* __restrict__ sub) {
    const int b    = blockIdx.y;
    const int lane = threadIdx.x & 63;
    const int wave = threadIdx.x >> 6;

    const float4* dv = (const float4*)(dec + (size_t)b * DEC);
    float4 q0 = dv[lane];
    float4 q1 = dv[lane + 64];

    const int e0 = blockIdx.x * 128 + wave * 32;
    for (int i = 0; i < 32; ++i) {
        const int e = e0 + i;
        const float4* wv = (const float4*)(W + (size_t)e * DEC);
        float4 w0 = wv[lane];
        float4 w1 = wv[lane + 64];
        float p = q0.x * w0.x + q0.y * w0.y + q0.z * w0.z + q0.w * w0.w
                + q1.x * w1.x + q1.y * w1.y + q1.z * w1.z + q1.w * w1.w;
        #pragma unroll
        for (int off = 32; off >= 1; off >>= 1) p += __shfl_xor(p, off, 64);
        if (lane == 0) sub[(size_t)b * ENC + e] = p;
    }
}

// ---------------------------------------------------------------------------
// Kernel 2: fused scores + online softmax + weighted accumulation.
// grid (NSPLIT, B), block 256 (4 waves). Each wave streams CHUNK/4 = 32 rows
// as TWO independent online-softmax chains (even/odd) to halve the serial
// reduce->exp->update chain and double memory in flight. Each row load is two
// fully-coalesced 1 KB global_load_dwordx4 wave accesses (ev[lane], ev[lane+64]).
// ---------------------------------------------------------------------------
__global__ __launch_bounds__(256) void k_attn(const float* __restrict__ enc,
                                              const float* __restrict__ sub,
                                              float* __restrict__ attn_raw,
                                              float* __restrict__ chunk_m,
                                              float* __restrict__ chunk_l,
                                              float* __restrict__ chunk_acc) {
    const int b    = blockIdx.y;
    const int c    = blockIdx.x;
    const int lane = threadIdx.x & 63;
    const int wave = threadIdx.x >> 6;

    const float4* qv = (const float4*)(sub + (size_t)b * ENC);
    float4 q0 = qv[lane];          // dims [4*lane .. 4*lane+3]
    float4 q1 = qv[lane + 64];     // dims [256+4*lane .. 256+4*lane+3]

    float mA = -INFINITY, lA = 0.f, mB = -INFINITY, lB = 0.f;
    float4 aA0 = {0,0,0,0}, aA1 = {0,0,0,0};
    float4 aB0 = {0,0,0,0}, aB1 = {0,0,0,0};

    const int sBase = c * CHUNK + wave;
    #pragma unroll 2
    for (int j = 0; j < CHUNK / 4; j += 2) {
        const int sA = sBase + 4 * j;
        const int sB = sA + 4;
        const float4* evA = (const float4*)(enc + ((size_t)b * SS + sA) * ENC);
        const float4* evB = (const float4*)(enc + ((size_t)b * SS + sB) * ENC);
        float4 eA0 = evA[lane];
        float4 eA1 = evA[lane + 64];
        float4 eB0 = evB[lane];
        float4 eB1 = evB[lane + 64];

        float pA = q0.x * eA0.x + q0.y * eA0.y + q0.z * eA0.z + q0.w * eA0.w
                 + q1.x * eA1.x + q1.y * eA1.y + q1.z * eA1.z + q1.w * eA1.w;
        float pB = q0.x * eB0.x + q0.y * eB0.y + q0.z * eB0.z + q0.w * eB0.w
                 + q1.x * eB1.x + q1.y * eB1.y + q1.z * eB1.z + q1.w * eB1.w;
        #pragma unroll
        for (int off = 32; off >= 1; off >>= 1) {
            pA += __shfl_xor(pA, off, 64);
            pB += __shfl_xor(pB, off, 64);
        }

        if (lane == 0) {
            attn_raw[(size_t)b * SS + sA] = pA;
            attn_raw[(size_t)b * SS + sB] = pB;
        }

        // chain A
        {
            const float mn = fmaxf(mA, pA);
            const float al = __expf(mA - mn);
            const float w  = __expf(pA - mn);
            lA = lA * al + w;
            aA0.x = aA0.x * al + w * eA0.x;  aA0.y = aA0.y * al + w * eA0.y;
            aA0.z = aA0.z * al + w * eA0.z;  aA0.w = aA0.w * al + w * eA0.w;
            aA1.x = aA1.x * al + w * eA1.x;  aA1.y = aA1.y * al + w * eA1.y;
            aA1.z = aA1.z * al + w * eA1.z;  aA1.w = aA1.w * al + w * eA1.w;
            mA = mn;
        }
        // chain B
        {
            const float mn = fmaxf(mB, pB);
            const float al = __expf(mB - mn);
            const float w  = __expf(pB - mn);
            lB = lB * al + w;
            aB0.x = aB0.x * al + w * eB0.x;  aB0.y = aB0.y * al + w * eB0.y;
            aB0.z = aB0.z * al + w * eB0.z;  aB0.w = aB0.w * al + w * eB0.w;
            aB1.x = aB1.x * al + w * eB1.x;  aB1.y = aB1.y * al + w * eB1.y;
            aB1.z = aB1.z * al + w * eB1.z;  aB1.w = aB1.w * al + w * eB1.w;
            mB = mn;
        }
    }

    // ---- merge the two chains of this wave ----
    const float mW = fmaxf(mA, mB);
    const float fA = __expf(mA - mW);
    const float fB = __expf(mB - mW);
    const float lw = lA * fA + lB * fB;
    float4 a0, a1;
    a0.x = aA0.x * fA + aB0.x * fB;  a0.y = aA0.y * fA + aB0.y * fB;
    a0.z = aA0.z * fA + aB0.z * fB;  a0.w = aA0.w * fA + aB0.w * fB;
    a1.x = aA1.x * fA + aB1.x * fB;  a1.y = aA1.y * fA + aB1.y * fB;
    a1.z = aA1.z * fA + aB1.z * fB;  a1.w = aA1.w * fA + aB1.w * fB;

    // ---- combine the 4 waves of this block ----
    __shared__ float sm[4];
    __shared__ float sl[4];
    __shared__ float sacc[4][ENC];

    if (lane == 0) sm[wave] = mW;
    __syncthreads();
    const float M = fmaxf(fmaxf(sm[0], sm[1]), fmaxf(sm[2], sm[3]));
    const float f = __expf(mW - M);           // wave-uniform
    if (lane == 0) sl[wave] = lw * f;
    float* sa = &sacc[wave][0];
    sa[4 * lane + 0]       = a0.x * f;  sa[4 * lane + 1]       = a0.y * f;
    sa[4 * lane + 2]       = a0.z * f;  sa[4 * lane + 3]       = a0.w * f;
    sa[256 + 4 * lane + 0] = a1.x * f;  sa[256 + 4 * lane + 1] = a1.y * f;
    sa[256 + 4 * lane + 2] = a1.z * f;  sa[256 + 4 * lane + 3] = a1.w * f;
    __syncthreads();

    const size_t idx = (size_t)b * NSPLIT + c;
    if (threadIdx.x == 0) {
        chunk_m[idx] = M;
        chunk_l[idx] = sl[0] + sl[1] + sl[2] + sl[3];
    }
    for (int e = threadIdx.x; e < ENC; e += 256) {
        chunk_acc[idx * ENC + e] = sacc[0][e] + sacc[1][e] + sacc[2][e] + sacc[3][e];
    }
}

// ---------------------------------------------------------------------------
// Kernel 3: combine chunks -> sumResult; normalize attn in place.
// grid (B, NSPLIT), block 256. y==0 also produces sumResult.
// ---------------------------------------------------------------------------
__global__ __launch_bounds__(256) void k_final(const float* __restrict__ chunk_m,
                                               const float* __restrict__ chunk_l,
                                               const float* __restrict__ chunk_acc,
                                               float* __restrict__ attn,
                                               float* __restrict__ sumResult) {
    const int b = blockIdx.x;
    const int y = blockIdx.y;

    float M = -INFINITY;
    #pragma unroll
    for (int c = 0; c < NSPLIT; ++c) M = fmaxf(M, chunk_m[(size_t)b * NSPLIT + c]);
    float L = 0.f;
    #pragma unroll
    for (int c = 0; c < NSPLIT; ++c)
        L += chunk_l[(size_t)b * NSPLIT + c] * __expf(chunk_m[(size_t)b * NSPLIT + c] - M);
    const float invL = 1.f / L;

    if (y == 0) {
        float f[NSPLIT];
        #pragma unroll
        for (int c = 0; c < NSPLIT; ++c)
            f[c] = __expf(chunk_m[(size_t)b * NSPLIT + c] - M);
        for (int e = threadIdx.x; e < ENC; e += 256) {
            float s = 0.f;
            #pragma unroll
            for (int c = 0; c < NSPLIT; ++c)
                s += chunk_acc[((size_t)b * NSPLIT + c) * ENC + e] * f[c];
            sumResult[(size_t)b * ENC + e] = s * invL;
        }
    }

    const int s0 = y * (SS / NSPLIT);   // 128-wide slice
    for (int s = s0 + threadIdx.x; s < s0 + SS / NSPLIT; s += 256) {
        const size_t i = (size_t)b * SS + s;
        attn[i] = __expf(attn[i] - M) * invL;
    }
}

// ---------------------------------------------------------------------------
extern "C" void kernel_launch(void* const* d_in, const int* in_sizes, int n_in,
                              void* d_out, int out_size, void* d_ws, size_t ws_size,
                              hipStream_t stream) {
    const float* dec = (const float*)d_in[0];   // [B,1,DEC]
    const float* enc = (const float*)d_in[1];   // [B,S,ENC]
    const float* W   = (const float*)d_in[2];   // [ENC,DEC]

    float* out       = (float*)d_out;
    float* attn      = out;                               // B*S
    float* sumResult = out + (size_t)BB * SS;             // B*ENC

    float* ws        = (float*)d_ws;
    float* sub       = ws;                                // B*ENC
    float* chunk_m   = sub + (size_t)BB * ENC;            // B*NSPLIT
    float* chunk_l   = chunk_m + (size_t)BB * NSPLIT;     // B*NSPLIT
    float* chunk_acc = chunk_l + (size_t)BB * NSPLIT;     // B*NSPLIT*ENC

    k_sub  <<<dim3(4, BB),       256, 0, stream>>>(dec, W, sub);
    k_attn <<<dim3(NSPLIT, BB),  256, 0, stream>>>(enc, sub, attn, chunk_m, chunk_l, chunk_acc);
    k_final<<<dim3(BB, NSPLIT),  256, 0, stream>>>(chunk_m, chunk_l, chunk_acc, attn, sumResult);
}